// Round 9
// baseline (73.556 us; speedup 1.0000x reference)
//
#include <hip/hip_runtime.h>

namespace {
constexpr int BATCH = 512;
constexpr int SEQL  = 512;
constexpr int HID   = 256;
constexpr int MORPH = 24;
constexpr float NEGV = -1.0e9f;
constexpr int NTHR  = 1024;
}

typedef float f4v __attribute__((ext_vector_type(4)));

__device__ __forceinline__ unsigned okey(float f) {
    unsigned u = __float_as_uint(f);
    return u ^ (unsigned)(((int)u >> 31) | 0x80000000);
}

// ---- Pre-kernel: order[] = b sorted by descending wl (stable). 1 block.
extern "C" __global__ __launch_bounds__(512)
void k_order(const int* __restrict__ wlen, int* __restrict__ order)
{
    __shared__ int s_wl[BATCH];
    const int t = threadIdx.x;
    s_wl[t] = wlen[t];
    __syncthreads();
    const int my = s_wl[t];
    int r = 0;
    for (int j = 0; j < BATCH; ++j) {
        const int wj = s_wl[j];
        r += (int)(wj > my) | ((int)(wj == my) & (int)(j < t));
    }
    order[r] = t;   // rank 0 = largest wl
}

// One block per batch row (via LPT complementary mapping). 1024 thr = 16 waves.
// P1: scores->keys, 4 rows/wave/iter. P2: radix select -> c2m.
// P3/P4 concurrent: waves 12-15 bpm (NT), waves 0-11 menc accumulate.
extern "C" __global__ __launch_bounds__(NTHR, 8)
void morphseg_kernel(const float* __restrict__ we,    // [B, L, H]
                     const int*   __restrict__ wlen,  // [B]
                     const int*   __restrict__ nmorph,// [B]
                     const float* __restrict__ Wv,    // [H]
                     const float* __restrict__ bias,  // [1]
                     const int*   __restrict__ order, // [B] desc-wl
                     float* __restrict__ out)         // menc [B*M*H] then bpm [B*L*M]
{
    // complementary pairing: co-resident blocks (i, i+256) get (heavy, light)
    const int i = blockIdx.x;
    const int b = (i < 256) ? order[i] : order[767 - i];

    const int tid  = threadIdx.x;
    const int lane = tid & 63;
    const int wave = tid >> 6;

    __shared__ unsigned s_keys[SEQL];                // 2 KB
    __shared__ int s_hist[256];                      // 1 KB
    __shared__ int s_c2m[SEQL];                      // 2 KB
    __shared__ float s_acc[MORPH][HID];              // 24 KB
    __shared__ unsigned long long s_eqm[8], s_ind[8];
    __shared__ unsigned s_p, s_T;
    __shared__ int s_Kr, s_KrF, s_done;

    const int wl = wlen[b];
    const int nm = nmorph[b];
    const int K  = nm - 1;
    const float b0 = bias[0];
    const float* __restrict__ werow = we + (size_t)b * (SEQL * HID);
    const unsigned KEYNEG = okey(NEGV);

    // ---- init
    if (tid < SEQL) s_keys[tid] = KEYNEG;
    {
        float* af = &s_acc[0][0];
        for (int i2 = tid; i2 < MORPH * HID; i2 += NTHR) af[i2] = 0.0f;
    }
    if (tid == 0) { s_p = 0u; s_Kr = K; s_done = 0; }
    __syncthreads();

    // ---- Phase 1: keys. 4 rows per wave per iter; lane = 16*rg + hg.
    {
        const int hg = lane & 15;          // h-slice: floats [hg*16, hg*16+16)
        const int rg = lane >> 4;          // row within the 4-row group
        const float4* __restrict__ W4 = reinterpret_cast<const float4*>(Wv);
        const float4 w0 = W4[hg * 4 + 0], w1 = W4[hg * 4 + 1];
        const float4 w2 = W4[hg * 4 + 2], w3 = W4[hg * 4 + 3];
        const int nvalid = wl - 1;
        for (int l0 = wave * 4; l0 < nvalid; l0 += 64) {
            const int row = l0 + rg;
            if (row < nvalid) {            // uniform per 16-lane group
                const float4* __restrict__ rp =
                    reinterpret_cast<const float4*>(werow + (size_t)row * HID);
                const float4 v0 = rp[hg * 4 + 0], v1 = rp[hg * 4 + 1];
                const float4 v2 = rp[hg * 4 + 2], v3 = rp[hg * 4 + 3];
                float d = v0.x * w0.x; d = fmaf(v0.y, w0.y, d);
                d = fmaf(v0.z, w0.z, d); d = fmaf(v0.w, w0.w, d);
                d = fmaf(v1.x, w1.x, d); d = fmaf(v1.y, w1.y, d);
                d = fmaf(v1.z, w1.z, d); d = fmaf(v1.w, w1.w, d);
                d = fmaf(v2.x, w2.x, d); d = fmaf(v2.y, w2.y, d);
                d = fmaf(v2.z, w2.z, d); d = fmaf(v2.w, w2.w, d);
                d = fmaf(v3.x, w3.x, d); d = fmaf(v3.y, w3.y, d);
                d = fmaf(v3.z, w3.z, d); d = fmaf(v3.w, w3.w, d);
                #pragma unroll
                for (int off = 1; off < 16; off <<= 1)
                    d += __shfl_xor(d, off, 64);
                if (hg == 0) s_keys[row] = okey(d + b0);
            }
        }
    }
    __syncthreads();

    // ---- Phase 2: radix select, MSB-first, early exit on exact boundary
    int done = 0;
    for (int pass = 0; pass < 4 && !done; ++pass) {
        const int shift = 24 - 8 * pass;
        if (tid < 256) s_hist[tid] = 0;
        __syncthreads();
        if (tid < SEQL) {
            const unsigned k = s_keys[tid];
            if (pass == 0 || (k >> (shift + 8)) == (s_p >> (shift + 8)))
                atomicAdd(&s_hist[(k >> shift) & 255], 1);
        }
        __syncthreads();
        if (wave == 0) {
            const int v0 = lane * 4;
            const int h0 = s_hist[v0], h1 = s_hist[v0 + 1];
            const int h2 = s_hist[v0 + 2], h3 = s_hist[v0 + 3];
            const int local = h0 + h1 + h2 + h3;
            int T = local;
            #pragma unroll
            for (int off = 1; off < 64; off <<= 1) {
                const int u = __shfl_down(T, off, 64);
                if (lane + off < 64) T += u;
            }
            const int A  = T - local;
            const int S3 = A + h3, S2 = S3 + h2, S1 = S2 + h1, S0 = S1 + h0;
            const int Kr = s_Kr;
            const unsigned p = s_p;
            int v = -1, Sv = 0, Sv1 = 0;
            if (A  < Kr && Kr <= S3) { v = v0 + 3; Sv = S3; Sv1 = A;  }
            if (S3 < Kr && Kr <= S2) { v = v0 + 2; Sv = S2; Sv1 = S3; }
            if (S2 < Kr && Kr <= S1) { v = v0 + 1; Sv = S1; Sv1 = S2; }
            if (S1 < Kr && Kr <= S0) { v = v0 + 0; Sv = S0; Sv1 = S1; }
            if (v >= 0) {
                const unsigned pv = p | ((unsigned)v << shift);
                if (Sv == Kr)        { s_T = pv - 1u; s_KrF = 0;        s_done = 1; }
                else if (shift == 0) { s_T = pv;      s_KrF = Kr - Sv1; s_done = 1; }
                else                 { s_p = pv;      s_Kr = Kr - Sv1; }
            }
        }
        __syncthreads();
        done = s_done;
    }

    // ---- separator flags (stable ties) -> c2m
    const unsigned Tf = s_T;
    const int KrF = s_KrF;
    const unsigned k = (tid < SEQL) ? s_keys[tid] : 0u;
    const bool gt = (tid < SEQL) && (k > Tf);
    const bool eq = (tid < SEQL) && (k == Tf);
    const unsigned long long eb = __ballot(eq);
    if (lane == 0 && wave < 8) s_eqm[wave] = eb;
    __syncthreads();

    auto prefix8 = [&](const unsigned long long* w8, int pos) -> int {
        const int wi = pos >> 6;
        const unsigned long long lowmask = (1ull << (pos & 63)) - 1ull;
        int r = 0;
        #pragma unroll
        for (int q2 = 0; q2 < 8; ++q2) {
            const unsigned long long w = w8[q2];
            r += (q2 < wi) ? __popcll(w) : ((q2 == wi) ? __popcll(w & lowmask) : 0);
        }
        return r;
    };

    int f = 0;
    if (tid < SEQL) f = gt || (eq && prefix8(s_eqm, tid) < KrF);
    const unsigned long long fb = __ballot(f);
    if (lane == 0 && wave < 8) s_ind[wave] = fb;
    __syncthreads();
    if (tid < SEQL) s_c2m[tid] = prefix8(s_ind, tid);
    __syncthreads();

    // ---- Phase 3+4 concurrent on disjoint waves
    if (wave >= 12) {
        // bpm one-hot (4 waves = 256 threads), NT float4 stores
        const int sub = tid - 768;
        float* __restrict__ bpm = out + (size_t)BATCH * MORPH * HID + (size_t)b * (SEQL * MORPH);
        for (int v = sub; v < SEQL * MORPH / 4; v += 256) {
            const int l  = v / 6;
            const int qv = v - l * 6;
            const int c  = s_c2m[l];
            const int mb = qv * 4;
            const bool valid = (l < wl);
            f4v o;
            o.x = (valid && c == mb + 0 && mb + 0 < nm) ? 1.0f : 0.0f;
            o.y = (valid && c == mb + 1 && mb + 1 < nm) ? 1.0f : 0.0f;
            o.z = (valid && c == mb + 2 && mb + 2 < nm) ? 1.0f : 0.0f;
            o.w = (valid && c == mb + 3 && mb + 3 < nm) ? 1.0f : 0.0f;
            __builtin_nontemporal_store(o, reinterpret_cast<f4v*>(bpm) + v);
        }
    } else {
        // menc: 12 waves, contiguous row chunks, LDS-atomic flush on morpheme change
        const int start = (wave * wl) / 12;
        const int end   = ((wave + 1) * wl) / 12;
        float4 acc = {0.f, 0.f, 0.f, 0.f};
        int mcur = -1;
        for (int l = start; l < end; ++l) {
            const int mm = s_c2m[l];           // wave-uniform broadcast
            if (mm != mcur) {                  // wave-uniform branch
                if (mcur >= 0) {
                    atomicAdd(&s_acc[mcur][lane * 4 + 0], acc.x);
                    atomicAdd(&s_acc[mcur][lane * 4 + 1], acc.y);
                    atomicAdd(&s_acc[mcur][lane * 4 + 2], acc.z);
                    atomicAdd(&s_acc[mcur][lane * 4 + 3], acc.w);
                    acc.x = acc.y = acc.z = acc.w = 0.f;
                }
                mcur = mm;
            }
            const float4 v = reinterpret_cast<const float4*>(werow + (size_t)l * HID)[lane];
            acc.x += v.x; acc.y += v.y; acc.z += v.z; acc.w += v.w;
        }
        if (mcur >= 0) {
            atomicAdd(&s_acc[mcur][lane * 4 + 0], acc.x);
            atomicAdd(&s_acc[mcur][lane * 4 + 1], acc.y);
            atomicAdd(&s_acc[mcur][lane * 4 + 2], acc.z);
            atomicAdd(&s_acc[mcur][lane * 4 + 3], acc.w);
        }
    }
    __syncthreads();

    // ---- write menc (NT float4)
    {
        float* __restrict__ mout = out + (size_t)b * (MORPH * HID);
        const f4v* af = reinterpret_cast<const f4v*>(&s_acc[0][0]);
        for (int i2 = tid; i2 < MORPH * HID / 4; i2 += NTHR)
            __builtin_nontemporal_store(af[i2], reinterpret_cast<f4v*>(mout) + i2);
    }
}

extern "C" void kernel_launch(void* const* d_in, const int* in_sizes, int n_in,
                              void* d_out, int out_size, void* d_ws, size_t ws_size,
                              hipStream_t stream) {
    const float* we     = (const float*)d_in[0];
    const int*   wlen   = (const int*)d_in[1];
    const int*   nmorph = (const int*)d_in[2];
    const float* Wv     = (const float*)d_in[3];
    const float* bias   = (const float*)d_in[4];
    float* out = (float*)d_out;

    int* order = (int*)d_ws;   // 2 KB, fully rewritten every launch

    k_order<<<dim3(1), dim3(512), 0, stream>>>(wlen, order);
    morphseg_kernel<<<dim3(BATCH), dim3(NTHR), 0, stream>>>(
        we, wlen, nmorph, Wv, bias, order, out);
}

// Round 10
// 70.558 us; speedup vs baseline: 1.0425x; 1.0425x over previous
//
#include <hip/hip_runtime.h>

namespace {
constexpr int BATCH = 512;
constexpr int SEQL  = 512;
constexpr int HID   = 256;
constexpr int MORPH = 24;
constexpr float NEGV = -1.0e9f;
constexpr int NTHR  = 1024;
constexpr int STASH = 56;     // rows of b2 cached in LDS for stage-5 menc
}

typedef float f4 __attribute__((ext_vector_type(4)));

__device__ __forceinline__ unsigned okey(float f) {
    unsigned u = __float_as_uint(f);
    return u ^ (unsigned)(((int)u >> 31) | 0x80000000);
}

__device__ __forceinline__ int prefix8(const unsigned long long* w8, int pos) {
    const int wi = pos >> 6;
    const unsigned long long lowmask = (1ull << (pos & 63)) - 1ull;
    int r = 0;
    #pragma unroll
    for (int q = 0; q < 8; ++q) {
        const unsigned long long w = w8[q];
        r += (q < wi) ? __popcll(w) : ((q == wi) ? __popcll(w & lowmask) : 0);
    }
    return r;
}

// radix select top-(nm-1) over s_keys -> s_c2m + s_sep. All 1024 threads.
__device__ __forceinline__ void select_c2m(
    int wl, int nm, int tid, int lane, int wave,
    unsigned* s_keys, int* s_hist, int* s_c2m, int* s_sep,
    unsigned long long* s_eqm, unsigned long long* s_ind,
    unsigned* s_p, unsigned* s_T, int* s_Kr, int* s_KrF, int* s_done)
{
    const int K = nm - 1;
    if (tid == 0) { *s_p = 0u; *s_Kr = K; *s_done = 0; }
    __syncthreads();

    int done = 0;
    for (int pass = 0; pass < 4 && !done; ++pass) {
        const int shift = 24 - 8 * pass;
        if (tid < 256) s_hist[tid] = 0;
        __syncthreads();
        if (tid < SEQL) {
            const unsigned k = s_keys[tid];
            if (pass == 0 || (k >> (shift + 8)) == (*s_p >> (shift + 8)))
                atomicAdd(&s_hist[(k >> shift) & 255], 1);
        }
        __syncthreads();
        if (wave == 0) {
            const int v0 = lane * 4;
            const int h0 = s_hist[v0], h1 = s_hist[v0 + 1];
            const int h2 = s_hist[v0 + 2], h3 = s_hist[v0 + 3];
            const int local = h0 + h1 + h2 + h3;
            int T = local;
            #pragma unroll
            for (int off = 1; off < 64; off <<= 1) {
                const int u = __shfl_down(T, off, 64);
                if (lane + off < 64) T += u;
            }
            const int A  = T - local;
            const int S3 = A + h3, S2 = S3 + h2, S1 = S2 + h1, S0 = S1 + h0;
            const int Kr = *s_Kr;
            const unsigned p = *s_p;
            int v = -1, Sv = 0, Sv1 = 0;
            if (A  < Kr && Kr <= S3) { v = v0 + 3; Sv = S3; Sv1 = A;  }
            if (S3 < Kr && Kr <= S2) { v = v0 + 2; Sv = S2; Sv1 = S3; }
            if (S2 < Kr && Kr <= S1) { v = v0 + 1; Sv = S1; Sv1 = S2; }
            if (S1 < Kr && Kr <= S0) { v = v0 + 0; Sv = S0; Sv1 = S1; }
            if (v >= 0) {
                const unsigned pv = p | ((unsigned)v << shift);
                if (Sv == Kr)        { *s_T = pv - 1u; *s_KrF = 0;        *s_done = 1; }
                else if (shift == 0) { *s_T = pv;      *s_KrF = Kr - Sv1; *s_done = 1; }
                else                 { *s_p = pv;      *s_Kr = Kr - Sv1; }
            }
        }
        __syncthreads();
        done = *s_done;
    }

    const unsigned Tf = *s_T;
    const int KrF = *s_KrF;
    const unsigned k = (tid < SEQL) ? s_keys[tid] : 0u;
    const bool gt = (tid < SEQL) && (k > Tf);
    const bool eq = (tid < SEQL) && (k == Tf);
    const unsigned long long eb = __ballot(eq);
    if (lane == 0 && wave < 8) s_eqm[wave] = eb;
    __syncthreads();
    int f = 0;
    if (tid < SEQL) f = gt || (eq && prefix8(s_eqm, tid) < KrF);
    const unsigned long long fb = __ballot(f);
    if (lane == 0 && wave < 8) s_ind[wave] = fb;
    __syncthreads();
    if (tid < SEQL) {
        const int cnt = prefix8(s_ind, tid);
        s_c2m[tid] = cnt;
        if (f) s_sep[cnt] = tid;     // cnt in [0,K): unique
    }
    __syncthreads();
}

// P1: keys for all rows (stride nw*4, 4 rows/wave-iter, 16 lanes per row).
// ST: also stash rows < STASH into LDS, and read through row wl-1.
template<bool ST>
__device__ __forceinline__ void p1_role(
    const float* __restrict__ werow, int wl, int nw, int wi,
    int hg, int rg, f4 w0, f4 w1, f4 w2, f4 w3, float b0,
    unsigned* s_keys, float (*stash)[HID])
{
    const int nvalid = wl - 1;
    const int rdmax  = ST ? wl : (wl - 1);
    const unsigned KEYNEG = okey(NEGV);
    for (int l0 = wi * 4; l0 < SEQL; l0 += nw * 4) {
        const int row = l0 + rg;
        float d = 0.f;
        if (row < rdmax) {                     // uniform per 16-lane group
            const f4* __restrict__ rp = reinterpret_cast<const f4*>(werow + (size_t)row * HID);
            const f4 v0 = rp[hg * 4 + 0], v1 = rp[hg * 4 + 1];
            const f4 v2 = rp[hg * 4 + 2], v3 = rp[hg * 4 + 3];
            const f4 p = v0 * w0 + v1 * w1 + v2 * w2 + v3 * w3;
            d = (p[0] + p[1]) + (p[2] + p[3]);
            if (ST && row < STASH) {
                f4* sp = reinterpret_cast<f4*>(&stash[row][hg * 16]);
                sp[0] = v0; sp[1] = v1; sp[2] = v2; sp[3] = v3;
            }
        }
        #pragma unroll
        for (int off = 1; off < 16; off <<= 1)
            d += __shfl_xor(d, off, 64);
        if (hg == 0) s_keys[row] = (row < nvalid) ? okey(d + b0) : KEYNEG;
    }
}

// menc for one morpheme m: segment sum, plain float4 store (exclusive owner).
template<bool ST>
__device__ __forceinline__ void menc_one(
    const float* __restrict__ werow, float* __restrict__ out, int b, int m,
    int wl, int nm, const int* s_sep, int lane, const float (*stash)[HID])
{
    f4 t = {0.f, 0.f, 0.f, 0.f};
    if (m < nm) {
        const int K  = nm - 1;
        const int lo = (m == 0) ? 0 : s_sep[m - 1] + 1;
        const int hi = (m < K) ? s_sep[m] : wl - 1;   // inclusive
        f4 a0 = {0.f,0.f,0.f,0.f}, a1 = {0.f,0.f,0.f,0.f};
        auto rd = [&](int l) -> f4 {
            if (ST && l < STASH) return *reinterpret_cast<const f4*>(&stash[l][lane * 4]);
            return reinterpret_cast<const f4*>(werow + (size_t)l * HID)[lane];
        };
        int l = lo;
        for (; l + 1 <= hi; l += 2) { a0 += rd(l); a1 += rd(l + 1); }
        if (l <= hi) a0 += rd(l);
        t = a0 + a1;
    }
    reinterpret_cast<f4*>(out + (size_t)b * (MORPH * HID) + (size_t)m * HID)[lane] = t;
}

// bpm one-hot for row b over thread-subset (sub in [0,cnt)), NT float4 stores.
__device__ __forceinline__ void bpm_role(
    float* __restrict__ out, int b, int wl, int nm, const int* s_c2m, int sub, int cnt)
{
    float* __restrict__ bpm = out + (size_t)BATCH * MORPH * HID + (size_t)b * (SEQL * MORPH);
    for (int v = sub; v < SEQL * MORPH / 4; v += cnt) {
        const int l  = v / 6;
        const int qv = v - l * 6;
        const int c  = s_c2m[l];
        const int mb = qv * 4;
        const bool valid = (l < wl);
        f4 o;
        o.x = (valid && c == mb + 0 && mb + 0 < nm) ? 1.0f : 0.0f;
        o.y = (valid && c == mb + 1 && mb + 1 < nm) ? 1.0f : 0.0f;
        o.z = (valid && c == mb + 2 && mb + 2 < nm) ? 1.0f : 0.0f;
        o.w = (valid && c == mb + 3 && mb + 3 < nm) ? 1.0f : 0.0f;
        __builtin_nontemporal_store(o, reinterpret_cast<f4*>(bpm) + v);
    }
}

// 256 blocks x 1024 thr; block i pipelines b1=i and b2=i+256 so the HBM read
// stream (P1 of b2) and the L3 re-read stream (menc of b1) run concurrently.
extern "C" __global__ __launch_bounds__(NTHR, 4)
void morphseg_pair(const float* __restrict__ we, const int* __restrict__ wlen,
                   const int* __restrict__ nmorph, const float* __restrict__ Wv,
                   const float* __restrict__ bias, float* __restrict__ out)
{
    const int b1 = blockIdx.x;
    const int b2 = blockIdx.x + 256;
    const int tid = threadIdx.x, lane = tid & 63, wave = tid >> 6;
    const int hg = lane & 15, rg = lane >> 4;

    __shared__ float s_stash[STASH][HID];            // 56 KB
    __shared__ unsigned s_keys[SEQL];                // 2 KB
    __shared__ int s_hist[256];                      // 1 KB
    __shared__ int s_c2m[SEQL];                      // 2 KB
    __shared__ int s_sep[32];
    __shared__ unsigned long long s_eqm[8], s_ind[8];
    __shared__ unsigned s_p, s_T;
    __shared__ int s_Kr, s_KrF, s_done;

    const float b0 = bias[0];
    const f4* __restrict__ W4 = reinterpret_cast<const f4*>(Wv);
    const f4 w0 = W4[hg * 4 + 0], w1 = W4[hg * 4 + 1];
    const f4 w2 = W4[hg * 4 + 2], w3 = W4[hg * 4 + 3];

    const int wl1 = wlen[b1], nm1 = nmorph[b1];
    const int wl2 = wlen[b2], nm2 = nmorph[b2];
    const float* __restrict__ we1 = we + (size_t)b1 * (SEQL * HID);
    const float* __restrict__ we2 = we + (size_t)b2 * (SEQL * HID);

    // ---- S1: P1(b1), all 16 waves
    p1_role<false>(we1, wl1, 16, wave, hg, rg, w0, w1, w2, w3, b0, s_keys, s_stash);
    __syncthreads();

    // ---- S2: select(b1)
    select_c2m(wl1, nm1, tid, lane, wave, s_keys, s_hist, s_c2m, s_sep,
               s_eqm, s_ind, &s_p, &s_T, &s_Kr, &s_KrF, &s_done);

    // ---- S3: menc(b1) [L3] || bpm(b1) [writes] || P1(b2) [HBM + stash]
    if (wave < 6) {
        #pragma unroll
        for (int j = 0; j < 4; ++j)
            menc_one<false>(we1, out, b1, wave * 4 + j, wl1, nm1, s_sep, lane, s_stash);
    } else if (wave < 8) {
        bpm_role(out, b1, wl1, nm1, s_c2m, tid - 384, 128);
    } else {
        p1_role<true>(we2, wl2, 8, wave - 8, hg, rg, w0, w1, w2, w3, b0, s_keys, s_stash);
    }
    __syncthreads();

    // ---- S4: select(b2)
    select_c2m(wl2, nm2, tid, lane, wave, s_keys, s_hist, s_c2m, s_sep,
               s_eqm, s_ind, &s_p, &s_T, &s_Kr, &s_KrF, &s_done);

    // ---- S5: menc(b2) [stash + L3] || bpm(b2)
    if (wave < 12) {
        #pragma unroll
        for (int j = 0; j < 2; ++j)
            menc_one<true>(we2, out, b2, wave * 2 + j, wl2, nm2, s_sep, lane, s_stash);
    } else {
        bpm_role(out, b2, wl2, nm2, s_c2m, tid - 768, 256);
    }
}

extern "C" void kernel_launch(void* const* d_in, const int* in_sizes, int n_in,
                              void* d_out, int out_size, void* d_ws, size_t ws_size,
                              hipStream_t stream) {
    const float* we     = (const float*)d_in[0];
    const int*   wlen   = (const int*)d_in[1];
    const int*   nmorph = (const int*)d_in[2];
    const float* Wv     = (const float*)d_in[3];
    const float* bias   = (const float*)d_in[4];
    float* out = (float*)d_out;

    morphseg_pair<<<dim3(BATCH / 2), dim3(NTHR), 0, stream>>>(
        we, wlen, nmorph, Wv, bias, out);
}